// Round 6
// baseline (246.403 us; speedup 1.0000x reference)
//
#include <hip/hip_runtime.h>

#define BATCH   32768
#define IN_DIM  256
#define OUT_DIM 256
#define NB      9      // real basis functions
#define NBP     12     // padded to 12 so BK=96 is a multiple of MFMA K=32
#define NKNOT   13
#define DEG     3

#define TM 64
#define TN 256
#define IC 8                 // input dims per K-chunk
#define BK (IC * NBP)        // 96 padded-k per chunk (3 MFMA k-steps)
#define SAS_A 104            // sA row stride: 208 B, 16-aligned, 2-way banks (verified shape)
#define THREADS 256
#define CHUNKS (IN_DIM / IC)         // 32
#define KSPLIT 2
#define HC (CHUNKS / KSPLIT)         // 16 chunks per k-half
#define SLAB (OUT_DIM * BK)          // dense bf16 elems per chunk slab in ws = 24576
#define WS_NEED ((size_t)CHUNKS * SLAB * 2)   // 1,572,864 B

typedef __bf16 bf16x8 __attribute__((ext_vector_type(8)));
typedef float  f32x4  __attribute__((ext_vector_type(4)));

// Cox-de-Boor with compile-time knots — verbatim from the passing kernels.
__device__ __forceinline__ void bspline9(float x, float bv[NB]) {
    const float t[NKNOT] = {-1.f, -1.f, -1.f, -1.f,
                            -2.f/3.f, -1.f/3.f, 0.f, 1.f/3.f, 2.f/3.f,
                            1.f, 1.f, 1.f, 1.f};
    float b[NKNOT - 1];
#pragma unroll
    for (int j = 0; j < NKNOT - 1; ++j)
        b[j] = (x >= t[j] && x < t[j + 1]) ? 1.f : 0.f;
    if (x >= t[NKNOT - 1]) b[8] = 1.f;
#pragma unroll
    for (int d = 1; d <= DEG; ++d) {
#pragma unroll
        for (int j = 0; j < NKNOT - 1 - d; ++j) {
            float d1 = t[j + d] - t[j];
            float d2 = t[j + d + 1] - t[j + 1];
            float w1 = (d1 > 0.f) ? (x - t[j]) * (1.f / d1) : 0.f;
            float w2 = (d2 > 0.f) ? (t[j + d + 1] - x) * (1.f / d2) : 0.f;
            b[j] = w1 * b[j] + w2 * b[j + 1];
        }
    }
#pragma unroll
    for (int r = 0; r < NB; ++r) bv[r] = b[r];
}

__device__ __forceinline__ unsigned packbf2(float a, float b) {
    unsigned ua = __float_as_uint(a);
    unsigned ub = __float_as_uint(b);
    ua += 0x7FFFu + ((ua >> 16) & 1u);
    ub += 0x7FFFu + ((ub >> 16) & 1u);
    return (ua >> 16) | (ub & 0xFFFF0000u);
}

// ---- pre-kernel: coeff fp32 -> bf16, dense per-chunk k-major layout ----
// ws[chunk][col][ii*12 + r]  (192 B per col per chunk, contiguous)
__global__ __launch_bounds__(256) void convert_coeff(
        const float* __restrict__ coeff, __bf16* __restrict__ ws)
{
    int p   = blockIdx.x * 256 + threadIdx.x;   // 65536 = 256 cols x 256 dims
    int col = p >> 8;
    int i   = p & 255;
    const float* cp = coeff + ((size_t)col * IN_DIM + i) * NB;
    unsigned d0 = packbf2(cp[0], cp[1]);
    unsigned d1 = packbf2(cp[2], cp[3]);
    unsigned d2 = packbf2(cp[4], cp[5]);
    unsigned d3 = packbf2(cp[6], cp[7]);
    unsigned d4 = packbf2(cp[8], 0.f);
    __bf16* dst = ws + (size_t)(i >> 3) * SLAB + (size_t)col * BK + (i & 7) * NBP;
    uint2* q = (uint2*)dst;                     // 24 B, 8-aligned
    q[0] = make_uint2(d0, d1);
    q[1] = make_uint2(d2, d3);
    q[2] = make_uint2(d4, 0u);
}

// ---- main: TM=64 x TN=256, K split in 2 across blockIdx.y (occupancy 2x).
//      A (basis) through LDS (4x reuse); B fragments straight from L2-resident ws.
//      Partials accumulated into pre-zeroed out via fp32 atomics.
__global__ __launch_bounds__(THREADS, 4) void kan_mfma5(
        const float* __restrict__ x,
        const __bf16* __restrict__ wsB,
        const float* __restrict__ bias,
        float* __restrict__ out)
{
    __shared__ __align__(16) __bf16 sA[TM][SAS_A];   // 13312 B

    const int tid  = threadIdx.x;
    const int m0   = blockIdx.x * TM;
    const int ky   = blockIdx.y;          // k-half
    const int lane = tid & 63;
    const int wave = tid >> 6;
    const int wn   = wave * 64;           // 4 waves tile the 256-wide N
    const int quad = lane >> 4;
    const int l16  = lane & 15;
    const int arow = tid >> 3;            // basis staging: rows arow, arow+32
    const int aii  = tid & 7;

    f32x4 acc[4][4] = {};   // [mt][nt]

    // B fragment base for this lane: col = wn + l16 (+nt*16), k-offset quad*8
    const __bf16* wb = wsB + (size_t)(wn + l16) * BK + quad * 8;

    for (int c = ky * HC; c < ky * HC + HC; ++c) {
        __syncthreads();   // previous iteration's sA reads complete

        // ---- stage A: 2 basis evals per thread (rows arow, arow+32) ----
#pragma unroll
        for (int h = 0; h < 2; ++h) {
            int row = arow + h * 32;
            float xv = x[(size_t)(m0 + row) * IN_DIM + c * IC + aii];
            float bv[NB];
            bspline9(xv, bv);
            uint2* dst = (uint2*)&sA[row][aii * NBP];
            dst[0] = make_uint2(packbf2(bv[0], bv[1]), packbf2(bv[2], bv[3]));
            dst[1] = make_uint2(packbf2(bv[4], bv[5]), packbf2(bv[6], bv[7]));
            dst[2] = make_uint2(packbf2(bv[8], 0.f), 0u);
        }

        // ---- B fragments: 12 x global b128 from L2-resident ws (short live range) ----
        uint4 breg[3][4];
        {
            const __bf16* wc = wb + (size_t)c * SLAB;
#pragma unroll
            for (int ks = 0; ks < 3; ++ks)
#pragma unroll
                for (int nt = 0; nt < 4; ++nt)
                    breg[ks][nt] = *(const uint4*)(wc + (size_t)nt * 16 * BK + ks * 32);
        }

        __syncthreads();   // sA published

        // ---- MFMA: 3 k-steps x 16 tiles (4x4), A from LDS, B from regs ----
#pragma unroll
        for (int ks = 0; ks < 3; ++ks) {
            bf16x8 af[4];
#pragma unroll
            for (int mt = 0; mt < 4; ++mt)
                af[mt] = *(const bf16x8*)&sA[mt * 16 + l16][ks * 32 + quad * 8];
#pragma unroll
            for (int mt = 0; mt < 4; ++mt)
#pragma unroll
                for (int nt = 0; nt < 4; ++nt)
                    acc[mt][nt] = __builtin_amdgcn_mfma_f32_16x16x32_bf16(
                        af[mt], *(const bf16x8*)&breg[ks][nt], acc[mt][nt], 0, 0, 0);
        }
    }

    // ---- epilogue: fp32 atomic accumulate (out pre-zeroed); ky==0 adds bias ----
#pragma unroll
    for (int nt = 0; nt < 4; ++nt) {
        int col = wn + nt * 16 + l16;
        float bs = (ky == 0) ? bias[col] : 0.f;
#pragma unroll
        for (int mt = 0; mt < 4; ++mt) {
            int row = m0 + mt * 16 + quad * 4;
#pragma unroll
            for (int r = 0; r < 4; ++r)
                atomicAdd(&out[(size_t)(row + r) * OUT_DIM + col], acc[mt][nt][r] + bs);
        }
    }
}

// ---- fallback (known-passing R2 kernel) if ws is too small ----
#define FTM 128
#define FTN 128
#define FSAS (96 + 8)
__global__ __launch_bounds__(256, 3) void kan_mfma_fb(
        const float* __restrict__ x,
        const float* __restrict__ coeff,
        const float* __restrict__ bias,
        float* __restrict__ out)
{
    __shared__ __align__(16) __bf16 sA[FTM][FSAS];
    __shared__ __align__(16) __bf16 sB[FTN][FSAS];
    const int tid  = threadIdx.x;
    const int m0   = blockIdx.x * FTM;
    const int n0   = blockIdx.y * FTN;
    const int lane = tid & 63;
    const int wave = tid >> 6;
    const int wm   = (wave & 1) * 64;
    const int wn   = (wave >> 1) * 64;
    const int quad = lane >> 4;
    const int l16  = lane & 15;
    f32x4 acc[4][4] = {};
    for (int i0 = 0; i0 < IN_DIM; i0 += IC) {
        __syncthreads();
#pragma unroll
        for (int q = 0; q < (FTM * IC) / 256; ++q) {
            int p   = tid + q * 256;
            int ii  = p & (IC - 1);
            int row = p >> 3;
            float xv = x[(size_t)(m0 + row) * IN_DIM + i0 + ii];
            float bv[NB];
            bspline9(xv, bv);
            uint2* dst = (uint2*)&sA[row][ii * NBP];
            dst[0] = make_uint2(packbf2(bv[0], bv[1]), packbf2(bv[2], bv[3]));
            dst[1] = make_uint2(packbf2(bv[4], bv[5]), packbf2(bv[6], bv[7]));
            dst[2] = make_uint2(packbf2(bv[8], 0.f), 0u);
        }
#pragma unroll
        for (int q = 0; q < (FTN * IC) / 256; ++q) {
            int p   = tid + q * 256;
            int ii  = p & (IC - 1);
            int col = p >> 3;
            const float* cp = &coeff[(size_t)(n0 + col) * (IN_DIM * NB)
                                     + (size_t)(i0 + ii) * NB];
            uint2* dst = (uint2*)&sB[col][ii * NBP];
            dst[0] = make_uint2(packbf2(cp[0], cp[1]), packbf2(cp[2], cp[3]));
            dst[1] = make_uint2(packbf2(cp[4], cp[5]), packbf2(cp[6], cp[7]));
            dst[2] = make_uint2(packbf2(cp[8], 0.f), 0u);
        }
        __syncthreads();
#pragma unroll
        for (int ks = 0; ks < BK / 32; ++ks) {
            bf16x8 af[4], bg[4];
#pragma unroll
            for (int mt = 0; mt < 4; ++mt)
                af[mt] = *(const bf16x8*)&sA[wm + mt * 16 + l16][ks * 32 + quad * 8];
#pragma unroll
            for (int nt = 0; nt < 4; ++nt)
                bg[nt] = *(const bf16x8*)&sB[wn + nt * 16 + l16][ks * 32 + quad * 8];
#pragma unroll
            for (int mt = 0; mt < 4; ++mt)
#pragma unroll
                for (int nt = 0; nt < 4; ++nt)
                    acc[mt][nt] = __builtin_amdgcn_mfma_f32_16x16x32_bf16(
                        af[mt], bg[nt], acc[mt][nt], 0, 0, 0);
        }
    }
#pragma unroll
    for (int nt = 0; nt < 4; ++nt) {
        int col = n0 + wn + nt * 16 + l16;
        float bs = bias[col];
#pragma unroll
        for (int mt = 0; mt < 4; ++mt) {
            int row = m0 + wm + mt * 16 + quad * 4;
#pragma unroll
            for (int r = 0; r < 4; ++r)
                out[(size_t)(row + r) * OUT_DIM + col] = acc[mt][nt][r] + bs;
        }
    }
}

extern "C" void kernel_launch(void* const* d_in, const int* in_sizes, int n_in,
                              void* d_out, int out_size, void* d_ws, size_t ws_size,
                              hipStream_t stream) {
    const float* x     = (const float*)d_in[0];   // (32768, 256)
    const float* coeff = (const float*)d_in[1];   // (256, 256, 9)
    const float* bias  = (const float*)d_in[2];   // (256,)
    float* out = (float*)d_out;                   // (32768, 256)

    if (ws_size >= WS_NEED) {
        __bf16* ws = (__bf16*)d_ws;
        hipMemsetAsync(d_out, 0, (size_t)out_size * sizeof(float), stream);
        convert_coeff<<<(OUT_DIM * IN_DIM) / 256, 256, 0, stream>>>(coeff, ws);
        kan_mfma5<<<dim3(BATCH / TM, KSPLIT), dim3(THREADS), 0, stream>>>(x, ws, bias, out);
    } else {
        dim3 grid(BATCH / FTM, OUT_DIM / FTN);
        kan_mfma_fb<<<grid, dim3(256), 0, stream>>>(x, coeff, bias, out);
    }
}

// Round 7
// 190.392 us; speedup vs baseline: 1.2942x; 1.2942x over previous
//
#include <hip/hip_runtime.h>

#define BATCH   32768
#define IN_DIM  256
#define OUT_DIM 256
#define NB      9      // real basis functions
#define NBP     12     // padded to 12 so BK=96 is a multiple of MFMA K=32
#define NKNOT   13
#define DEG     3

#define TM 32
#define TN 256
#define IC 8                 // input dims per K-chunk
#define BK (IC * NBP)        // 96 padded-k per chunk (3 MFMA k-steps)
#define SAS_A 104            // sA row stride: 208 B, 16-aligned, 2-way banks (verified shape)
#define THREADS 256
#define CHUNKS (IN_DIM / IC)         // 32
#define SLAB (OUT_DIM * BK)          // dense bf16 elems per chunk slab in ws = 24576
#define WS_NEED ((size_t)CHUNKS * SLAB * 2)   // 1,572,864 B

typedef __bf16 bf16x8 __attribute__((ext_vector_type(8)));
typedef float  f32x4  __attribute__((ext_vector_type(4)));

// Cox-de-Boor with compile-time knots — verbatim from the passing kernels.
__device__ __forceinline__ void bspline9(float x, float bv[NB]) {
    const float t[NKNOT] = {-1.f, -1.f, -1.f, -1.f,
                            -2.f/3.f, -1.f/3.f, 0.f, 1.f/3.f, 2.f/3.f,
                            1.f, 1.f, 1.f, 1.f};
    float b[NKNOT - 1];
#pragma unroll
    for (int j = 0; j < NKNOT - 1; ++j)
        b[j] = (x >= t[j] && x < t[j + 1]) ? 1.f : 0.f;
    if (x >= t[NKNOT - 1]) b[8] = 1.f;
#pragma unroll
    for (int d = 1; d <= DEG; ++d) {
#pragma unroll
        for (int j = 0; j < NKNOT - 1 - d; ++j) {
            float d1 = t[j + d] - t[j];
            float d2 = t[j + d + 1] - t[j + 1];
            float w1 = (d1 > 0.f) ? (x - t[j]) * (1.f / d1) : 0.f;
            float w2 = (d2 > 0.f) ? (t[j + d + 1] - x) * (1.f / d2) : 0.f;
            b[j] = w1 * b[j] + w2 * b[j + 1];
        }
    }
#pragma unroll
    for (int r = 0; r < NB; ++r) bv[r] = b[r];
}

__device__ __forceinline__ unsigned packbf2(float a, float b) {
    unsigned ua = __float_as_uint(a);
    unsigned ub = __float_as_uint(b);
    ua += 0x7FFFu + ((ua >> 16) & 1u);
    ub += 0x7FFFu + ((ub >> 16) & 1u);
    return (ua >> 16) | (ub & 0xFFFF0000u);
}

// ---- pre-kernel: coeff fp32 -> bf16, dense per-chunk k-major layout ----
// ws[chunk][col][ii*12 + r]  (192 B per col per chunk, contiguous)
__global__ __launch_bounds__(256) void convert_coeff(
        const float* __restrict__ coeff, __bf16* __restrict__ ws)
{
    int p   = blockIdx.x * 256 + threadIdx.x;   // 65536 = 256 cols x 256 dims
    int col = p >> 8;
    int i   = p & 255;
    const float* cp = coeff + ((size_t)col * IN_DIM + i) * NB;
    unsigned d0 = packbf2(cp[0], cp[1]);
    unsigned d1 = packbf2(cp[2], cp[3]);
    unsigned d2 = packbf2(cp[4], cp[5]);
    unsigned d3 = packbf2(cp[6], cp[7]);
    unsigned d4 = packbf2(cp[8], 0.f);
    __bf16* dst = ws + (size_t)(i >> 3) * SLAB + (size_t)col * BK + (i & 7) * NBP;
    uint2* q = (uint2*)dst;                     // 24 B, 8-aligned
    q[0] = make_uint2(d0, d1);
    q[1] = make_uint2(d2, d3);
    q[2] = make_uint2(d4, 0u);
}

// ---- main: TM=32 x TN=256, 256 thr = 4 waves of 32x64 (acc 2x4), full K per
//      block -> direct stores. Grid 1024 = 4 blocks/CU (16 waves/CU).
//      sA double-buffered -> ONE barrier per chunk. B straight from L2 ws.
__global__ __launch_bounds__(THREADS, 4) void kan_mfma6(
        const float* __restrict__ x,
        const __bf16* __restrict__ wsB,
        const float* __restrict__ bias,
        float* __restrict__ out)
{
    __shared__ __align__(16) __bf16 sA[2][TM][SAS_A];   // 13312 B total

    const int tid  = threadIdx.x;
    const int m0   = blockIdx.x * TM;
    const int lane = tid & 63;
    const int wave = tid >> 6;
    const int wn   = wave * 64;           // 4 waves tile the 256-wide N
    const int quad = lane >> 4;
    const int l16  = lane & 15;
    const int arow = tid >> 3;            // basis staging: row 0..31
    const int aii  = tid & 7;

    f32x4 acc[2][4] = {};   // [mt][nt]

    // B fragment base for this lane: col = wn + l16 (+nt*16), k-offset quad*8
    const __bf16* wb = wsB + (size_t)(wn + l16) * BK + quad * 8;

    for (int c = 0; c < CHUNKS; ++c) {
        const int buf = c & 1;

        // ---- stage A: one basis eval per thread (32 rows x 8 dims) ----
        {
            float xv = x[(size_t)(m0 + arow) * IN_DIM + c * IC + aii];
            float bv[NB];
            bspline9(xv, bv);
            uint2* dst = (uint2*)&sA[buf][arow][aii * NBP];
            dst[0] = make_uint2(packbf2(bv[0], bv[1]), packbf2(bv[2], bv[3]));
            dst[1] = make_uint2(packbf2(bv[4], bv[5]), packbf2(bv[6], bv[7]));
            dst[2] = make_uint2(packbf2(bv[8], 0.f), 0u);
        }

        // ---- B fragments: 12 x global b128 from L2-resident ws (short live range) ----
        uint4 breg[3][4];
        {
            const __bf16* wc = wb + (size_t)c * SLAB;
#pragma unroll
            for (int ks = 0; ks < 3; ++ks)
#pragma unroll
                for (int nt = 0; nt < 4; ++nt)
                    breg[ks][nt] = *(const uint4*)(wc + (size_t)nt * 16 * BK + ks * 32);
        }

        // single barrier: publishes sA[buf]; safety of overwriting sA[buf]
        // (last read at chunk c-2) is guaranteed by the barrier at c-1.
        __syncthreads();

        // ---- MFMA: 3 k-steps x 8 tiles (2x4), A from LDS, B from regs ----
#pragma unroll
        for (int ks = 0; ks < 3; ++ks) {
            bf16x8 af[2];
#pragma unroll
            for (int mt = 0; mt < 2; ++mt)
                af[mt] = *(const bf16x8*)&sA[buf][mt * 16 + l16][ks * 32 + quad * 8];
#pragma unroll
            for (int mt = 0; mt < 2; ++mt)
#pragma unroll
                for (int nt = 0; nt < 4; ++nt)
                    acc[mt][nt] = __builtin_amdgcn_mfma_f32_16x16x32_bf16(
                        af[mt], *(const bf16x8*)&breg[ks][nt], acc[mt][nt], 0, 0, 0);
        }
    }

    // ---- epilogue: D row = quad*4+reg, col = l16; direct stores ----
#pragma unroll
    for (int nt = 0; nt < 4; ++nt) {
        int col = wn + nt * 16 + l16;
        float bs = bias[col];
#pragma unroll
        for (int mt = 0; mt < 2; ++mt) {
            int row = m0 + mt * 16 + quad * 4;
#pragma unroll
            for (int r = 0; r < 4; ++r)
                out[(size_t)(row + r) * OUT_DIM + col] = acc[mt][nt][r] + bs;
        }
    }
}

// ---- fallback (known-passing R2 kernel) if ws is too small ----
#define FTM 128
#define FTN 128
#define FSAS (96 + 8)
__global__ __launch_bounds__(256, 3) void kan_mfma_fb(
        const float* __restrict__ x,
        const float* __restrict__ coeff,
        const float* __restrict__ bias,
        float* __restrict__ out)
{
    __shared__ __align__(16) __bf16 sA[FTM][FSAS];
    __shared__ __align__(16) __bf16 sB[FTN][FSAS];
    const int tid  = threadIdx.x;
    const int m0   = blockIdx.x * FTM;
    const int n0   = blockIdx.y * FTN;
    const int lane = tid & 63;
    const int wave = tid >> 6;
    const int wm   = (wave & 1) * 64;
    const int wn   = (wave >> 1) * 64;
    const int quad = lane >> 4;
    const int l16  = lane & 15;
    f32x4 acc[4][4] = {};
    for (int i0 = 0; i0 < IN_DIM; i0 += IC) {
        __syncthreads();
#pragma unroll
        for (int q = 0; q < (FTM * IC) / 256; ++q) {
            int p   = tid + q * 256;
            int ii  = p & (IC - 1);
            int row = p >> 3;
            float xv = x[(size_t)(m0 + row) * IN_DIM + i0 + ii];
            float bv[NB];
            bspline9(xv, bv);
            uint2* dst = (uint2*)&sA[row][ii * NBP];
            dst[0] = make_uint2(packbf2(bv[0], bv[1]), packbf2(bv[2], bv[3]));
            dst[1] = make_uint2(packbf2(bv[4], bv[5]), packbf2(bv[6], bv[7]));
            dst[2] = make_uint2(packbf2(bv[8], 0.f), 0u);
        }
#pragma unroll
        for (int q = 0; q < (FTN * IC) / 256; ++q) {
            int p   = tid + q * 256;
            int ii  = p & (IC - 1);
            int col = p >> 3;
            const float* cp = &coeff[(size_t)(n0 + col) * (IN_DIM * NB)
                                     + (size_t)(i0 + ii) * NB];
            uint2* dst = (uint2*)&sB[col][ii * NBP];
            dst[0] = make_uint2(packbf2(cp[0], cp[1]), packbf2(cp[2], cp[3]));
            dst[1] = make_uint2(packbf2(cp[4], cp[5]), packbf2(cp[6], cp[7]));
            dst[2] = make_uint2(packbf2(cp[8], 0.f), 0u);
        }
        __syncthreads();
#pragma unroll
        for (int ks = 0; ks < BK / 32; ++ks) {
            bf16x8 af[4], bg[4];
#pragma unroll
            for (int mt = 0; mt < 4; ++mt)
                af[mt] = *(const bf16x8*)&sA[wm + mt * 16 + l16][ks * 32 + quad * 8];
#pragma unroll
            for (int nt = 0; nt < 4; ++nt)
                bg[nt] = *(const bf16x8*)&sB[wn + nt * 16 + l16][ks * 32 + quad * 8];
#pragma unroll
            for (int mt = 0; mt < 4; ++mt)
#pragma unroll
                for (int nt = 0; nt < 4; ++nt)
                    acc[mt][nt] = __builtin_amdgcn_mfma_f32_16x16x32_bf16(
                        af[mt], bg[nt], acc[mt][nt], 0, 0, 0);
        }
    }
#pragma unroll
    for (int nt = 0; nt < 4; ++nt) {
        int col = n0 + wn + nt * 16 + l16;
        float bs = bias[col];
#pragma unroll
        for (int mt = 0; mt < 4; ++mt) {
            int row = m0 + wm + mt * 16 + quad * 4;
#pragma unroll
            for (int r = 0; r < 4; ++r)
                out[(size_t)(row + r) * OUT_DIM + col] = acc[mt][nt][r] + bs;
        }
    }
}

extern "C" void kernel_launch(void* const* d_in, const int* in_sizes, int n_in,
                              void* d_out, int out_size, void* d_ws, size_t ws_size,
                              hipStream_t stream) {
    const float* x     = (const float*)d_in[0];   // (32768, 256)
    const float* coeff = (const float*)d_in[1];   // (256, 256, 9)
    const float* bias  = (const float*)d_in[2];   // (256,)
    float* out = (float*)d_out;                   // (32768, 256)

    if (ws_size >= WS_NEED) {
        __bf16* ws = (__bf16*)d_ws;
        convert_coeff<<<(OUT_DIM * IN_DIM) / 256, 256, 0, stream>>>(coeff, ws);
        kan_mfma6<<<dim3(BATCH / TM), dim3(THREADS), 0, stream>>>(x, ws, bias, out);
    } else {
        dim3 grid(BATCH / FTM, OUT_DIM / FTN);
        kan_mfma_fb<<<grid, dim3(256), 0, stream>>>(x, coeff, bias, out);
    }
}